// Round 17
// baseline (146.523 us; speedup 1.0000x reference)
//
#include <hip/hip_runtime.h>
#include <math.h>

#define HID 128
#define TPB 512   // 8 waves/block
#define NW  8
#define GRIDB 1024 // 4 blocks/CU x 256 CUs; 8192 waves x 16 samples = 131072 = B

typedef __bf16 bf16;
typedef bf16 bf16x8 __attribute__((ext_vector_type(8)));
typedef bf16 bf16x4 __attribute__((ext_vector_type(4)));
typedef float floatx4 __attribute__((ext_vector_type(4)));

__device__ __forceinline__ floatx4 tanh4(floatx4 z) {
    floatx4 t = z * 2.885390081777927f;
    floatx4 e = { __builtin_amdgcn_exp2f(t[0]), __builtin_amdgcn_exp2f(t[1]),
                  __builtin_amdgcn_exp2f(t[2]), __builtin_amdgcn_exp2f(t[3]) };
    e = e + 1.0f;
    floatx4 r = { __builtin_amdgcn_rcpf(e[0]), __builtin_amdgcn_rcpf(e[1]),
                  __builtin_amdgcn_rcpf(e[2]), __builtin_amdgcn_rcpf(e[3]) };
    return 1.0f - 2.0f * r;
}

// MAX-OCCUPANCY round. Session findings driving this design:
//  - allocator pins 64 arch-VGPRs (live>~64 => 200MB scratch spill). Frame
//    fits 64. At 64 VGPRs the HW allows 32 waves/CU (pool 2048/64).
//  - previous cap was LDS: two 32KB weight frag images => 79.5KB/block =>
//    2 blocks/CU => 16 waves/CU (4/SIMD). All pipes half-idle (VALU 50%,
//    Mfma 17%); latency-bound with distributed cost (r13 ablation).
//  - THIS round: weight images move to GLOBAL (d_ws), pre-baked in frag-line
//    layout by a prep kernel so each A-line read is ONE coalesced
//    global_load_dwordx4 (L1/L2-hot: 64KB total, 32KB per GEMM phase = L1).
//    LDS 15.5KB => 4 blocks/CU => 32 waves/CU (8/SIMD), 2x latency hiding.
//    Grid 1024 blocks = 1 tile/wave, all resident, no tail, no per-block
//    weight gather staging.
//  - setprio kept (r16: neutral-to-slightly-positive, zero cost).
//  - skew/dual-tile/barrier levers measured null or negative (r6/r9/r15).
//
// MFMA 16x16x32 layouts:
//   A-frag: lane holds A[m=lane&15][k=(lane>>4)*8+idx]
//   B-frag: lane holds B[k=(lane>>4)*8+idx][n=lane&15]
//   C/D:    lane/reg holds D[row=(lane>>4)*4+reg][col=lane&15]
// Sample ALWAYS = lane&15. P1 makes H1^T B-frags directly in regs (breg).
// GEMM1t: Z2^T = W2^T @ H1^T (A-lines from wsA image, B=breg)
// GEMM2t: S^T  = W2 @ G2^T   (A-lines from wsR image, B=gB via transform)
// GEMM3t: dV^T = W1 @ G1^T   (A=sW1A LDS lines, B=(1-breg^2)*transform(S))
// C->B transform (HW-verified r7-r16): line L, b: elem = lrow*32 + blk*8 +
// 4(lq&1)+r, blk=(2b+(lq>>1))^(lrow&3); read b128 at lrow*32+(lq^(lrow&3))*8.
// DS in-order per wave => write->read needs no barrier.
// ws layout: [0,16384) bf16 = image1 (W2^T A-frags: slot e=(jt*4+kt)*64+lane,
// value W2[32kt+8q+idx][16jt+lr]); [16384,32768) = image2 (W2 row A-frags:
// slot e=(it*4+jt2)*64+lane, value W2[16it+lr][32jt2+8q+idx]). 64KB total.

__global__ __launch_bounds__(256)
void prep_kernel(const float* __restrict__ W2, bf16* __restrict__ ws)
{
    int e = (int)blockIdx.x * 256 + threadIdx.x;   // 0..4095
    if (e < 2048) { // image1: W2^T A-frags (column gather)
        int t = e >> 6, l = e & 63;
        int jt = t >> 2, kt = t & 3;
        int lr = l & 15, q = l >> 4;
        bf16x8 f;
        #pragma unroll
        for (int idx = 0; idx < 8; ++idx)
            f[idx] = (bf16)W2[(32*kt + 8*q + idx) * HID + 16*jt + lr];
        *reinterpret_cast<bf16x8*>(&ws[e * 8]) = f;
    } else {        // image2: W2 row A-frags (coalesced row reads)
        int e2 = e - 2048;
        int t = e2 >> 6, l = e2 & 63;
        int it = t >> 2, jt2 = t & 3;
        int lr = l & 15, q = l >> 4;
        const float4* rp = reinterpret_cast<const float4*>(&W2[(16*it + lr) * HID + 32*jt2 + 8*q]);
        float4 r0 = rp[0], r1 = rp[1];
        bf16x8 g;
        g[0]=(bf16)r0.x; g[1]=(bf16)r0.y; g[2]=(bf16)r0.z; g[3]=(bf16)r0.w;
        g[4]=(bf16)r1.x; g[5]=(bf16)r1.y; g[6]=(bf16)r1.z; g[7]=(bf16)r1.w;
        *reinterpret_cast<bf16x8*>(&ws[16384 + e2 * 8]) = g;
    }
}

__global__ __launch_bounds__(TPB, 4)
void lnn_kernel(const float* __restrict__ X,
                const float* __restrict__ W1,
                const float* __restrict__ b1,
                const float* __restrict__ b2,
                const float* __restrict__ W3,
                const bf16* __restrict__ ws,
                float* __restrict__ out,
                int B, int nchunk)
{
    __shared__ __align__(16) bf16 sXf[NW][512]; // 8KB per-wave line buffers
    __shared__ __align__(16) bf16 sW1A[4][512]; // 4KB W1 A-frag lines
    __shared__ __align__(16) float sW1r[4][HID]; // 2KB
    __shared__ __align__(16) float sB1[HID], sB2[HID], sW3[HID]; // 1.5KB
    // total 15.5KB -> 4 blocks/CU -> 32 waves/CU

    const int tid  = threadIdx.x;
    const int w    = tid >> 6;
    const int lane = tid & 63;
    const int lrow = lane & 15;
    const int lq   = lane >> 4;
    const int swz  = lrow & 3;

    const bf16* const wsA = ws;           // image1: GEMM1 A-lines
    const bf16* const wsR = ws + 16384;   // image2: GEMM2 A-lines

    { int r = tid >> 7, j = tid & (HID - 1); sW1r[r][j] = W1[r * HID + j]; }
    if (tid < HID) sB1[tid] = b1[tid];
    else if (tid < 2 * HID) sB2[tid - HID] = b2[tid - HID];
    else if (tid < 3 * HID) sW3[tid - 2 * HID] = W3[tid - 2 * HID];
    if (tid < 256) { // W1 A-frag lines: A[m=lr][k=32m+8q+idx], rows>=4 zero
        int m = tid >> 6, l = tid & 63;
        int lr = l & 15, q = l >> 4;
        bf16x8 f = {};
        if (lr < 4) {
            #pragma unroll
            for (int idx = 0; idx < 8; ++idx)
                f[idx] = (bf16)W1[lr * HID + 32*m + 8*q + idx];
        }
        *reinterpret_cast<bf16x8*>(&sW1A[m][l * 8]) = f;
    }
    __syncthreads(); // only barrier

    bf16* const lb = &sXf[w][0];
    const int tileStride = GRIDB * NW;
    const int t0 = (int)blockIdx.x * NW + w;
    const floatx4 fz = floatx4{0.f,0.f,0.f,0.f};

    #pragma unroll 1
    for (int c = 0; c < nchunk; ++c) {
        const int tile = t0 + c * tileStride;
        if (tile * 16 >= B) break;
        const int S0 = tile * 16;

        int gc = S0 + lrow; gc = gc < B ? gc : (B - 1);
        float4 xc = reinterpret_cast<const float4*>(X)[gc];
        float s1c, c1c, s2c, c2c;
        __sincosf(xc.x, &s1c, &c1c);
        __sincosf(xc.y, &s2c, &c2c);

        // ---- P1: feat -> H1^T B-frags in regs ----
        bf16x8 bregc[4];
        #pragma unroll
        for (int kt = 0; kt < 4; ++kt) {
            int jb = 32 * kt + 8 * lq;
            floatx4 w0a = *reinterpret_cast<const floatx4*>(&sW1r[0][jb]);
            floatx4 w0b = *reinterpret_cast<const floatx4*>(&sW1r[0][jb+4]);
            floatx4 w1a = *reinterpret_cast<const floatx4*>(&sW1r[1][jb]);
            floatx4 w1b = *reinterpret_cast<const floatx4*>(&sW1r[1][jb+4]);
            floatx4 w2a = *reinterpret_cast<const floatx4*>(&sW1r[2][jb]);
            floatx4 w2b = *reinterpret_cast<const floatx4*>(&sW1r[2][jb+4]);
            floatx4 w3a = *reinterpret_cast<const floatx4*>(&sW1r[3][jb]);
            floatx4 w3b = *reinterpret_cast<const floatx4*>(&sW1r[3][jb+4]);
            floatx4 bba = *reinterpret_cast<const floatx4*>(&sB1[jb]);
            floatx4 bbb = *reinterpret_cast<const floatx4*>(&sB1[jb+4]);
            floatx4 za = bba + s1c*w0a + c1c*w1a + s2c*w2a + c2c*w3a;
            floatx4 zb = bbb + s1c*w0b + c1c*w1b + s2c*w2b + c2c*w3b;
            floatx4 ha = tanh4(za), hb = tanh4(zb);
            bf16x8 hf;
            hf[0]=(bf16)ha[0]; hf[1]=(bf16)ha[1]; hf[2]=(bf16)ha[2]; hf[3]=(bf16)ha[3];
            hf[4]=(bf16)hb[0]; hf[5]=(bf16)hb[1]; hf[6]=(bf16)hb[2]; hf[7]=(bf16)hb[3];
            bregc[kt] = hf;
        }

        // ---- GEMM1 + P3 writes + gB reads (A-lines from wsA via L1/L2) ----
        bf16x8 gB[4];
        #pragma unroll
        for (int L = 0; L < 4; ++L) {
            #pragma unroll
            for (int b = 0; b < 2; ++b) {
                int jt = 2*L + b;
                __builtin_amdgcn_s_setprio(1);
                floatx4 acc = __builtin_amdgcn_mfma_f32_16x16x32_bf16(
                    *reinterpret_cast<const bf16x8*>(&wsA[((jt*4 + 0)*64 + lane)*8]),
                    bregc[0], fz, 0,0,0);
                #pragma unroll
                for (int kt = 1; kt < 4; ++kt)
                    acc = __builtin_amdgcn_mfma_f32_16x16x32_bf16(
                        *reinterpret_cast<const bf16x8*>(&wsA[((jt*4 + kt)*64 + lane)*8]),
                        bregc[kt], acc, 0,0,0);
                __builtin_amdgcn_s_setprio(0);
                int jb = 16*jt + 4*lq;
                floatx4 b2v = *reinterpret_cast<const floatx4*>(&sB2[jb]);
                floatx4 w3v = *reinterpret_cast<const floatx4*>(&sW3[jb]);
                floatx4 h = tanh4(acc + b2v);
                floatx4 gv = (1.0f - h*h) * w3v;
                bf16x4 g;
                g[0]=(bf16)gv[0]; g[1]=(bf16)gv[1]; g[2]=(bf16)gv[2]; g[3]=(bf16)gv[3];
                int blk = (2*b + (lq>>1)) ^ swz;
                *reinterpret_cast<bf16x4*>(&lb[lrow*32 + blk*8 + 4*(lq&1)]) = g;
            }
            gB[L] = *reinterpret_cast<const bf16x8*>(&lb[lrow*32 + (lq ^ swz)*8]);
        }

        // ---- GEMM2 + P5 writes + GEMM3 (A-lines from wsR via L1/L2) ----
        floatx4 dv = fz;
        #pragma unroll
        for (int L = 0; L < 4; ++L) {
            #pragma unroll
            for (int b = 0; b < 2; ++b) {
                int it = 2*L + b;
                __builtin_amdgcn_s_setprio(1);
                floatx4 acc2 = __builtin_amdgcn_mfma_f32_16x16x32_bf16(
                    *reinterpret_cast<const bf16x8*>(&wsR[((it*4 + 0)*64 + lane)*8]),
                    gB[0], fz, 0,0,0);
                #pragma unroll
                for (int jt2 = 1; jt2 < 4; ++jt2)
                    acc2 = __builtin_amdgcn_mfma_f32_16x16x32_bf16(
                        *reinterpret_cast<const bf16x8*>(&wsR[((it*4 + jt2)*64 + lane)*8]),
                        gB[jt2], acc2, 0,0,0);
                __builtin_amdgcn_s_setprio(0);
                bf16x4 g;
                g[0]=(bf16)acc2[0]; g[1]=(bf16)acc2[1];
                g[2]=(bf16)acc2[2]; g[3]=(bf16)acc2[3];
                int blk = (2*b + (lq>>1)) ^ swz;
                *reinterpret_cast<bf16x4*>(&lb[lrow*32 + blk*8 + 4*(lq&1)]) = g;
            }
            bf16x8 sv = *reinterpret_cast<const bf16x8*>(&lb[lrow*32 + (lq ^ swz)*8]);
            bf16x8 A3 = *reinterpret_cast<const bf16x8*>(&sW1A[L][lane*8]);
            bf16x8 g1;
            #pragma unroll
            for (int idx = 0; idx < 8; ++idx) {
                float h = (float)bregc[L][idx];
                float s = (float)sv[idx];
                g1[idx] = (bf16)(s - s*h*h);
            }
            __builtin_amdgcn_s_setprio(1);
            dv = __builtin_amdgcn_mfma_f32_16x16x32_bf16(A3, g1, dv, 0,0,0);
            __builtin_amdgcn_s_setprio(0);
        }

        // ---- Epilogue: lanes 0..15 hold dv rows 0..3 for sample lrow ----
        if (lane < 16 && S0 + lane < B) {
            float dV0 = dv[0], dV1 = dv[1], dV2 = dv[2], dV3 = dv[3];
            float cosD = c1c * c2c + s1c * s2c;
            float sinD = s1c * c2c - c1c * s2c;
            float dVt1 = dV0 * c1c - dV1 * s1c;   // dV/dt1
            float dVt2 = dV2 * c2c - dV3 * s2c;   // dV/dt2
            float qd1 = xc.z, qd2 = xc.w;
            float sT = qd1 * qd2 * sinD;          // dT/dt1 = -sT, dT/dt2 = +sT
            float cw = sinD * (qd2 - qd1);
            float rhs1 = (-sT - dVt1) - qd2 * cw;
            float rhs2 = ( sT - dVt2) - qd1 * cw;
            float det = 2.0f - cosD * cosD;       // det(M) in [1,2]
            float inv = __builtin_amdgcn_rcpf(det);
            float qdd1 = (rhs1 - cosD * rhs2) * inv;
            float qdd2 = (2.0f * rhs2 - cosD * rhs1) * inv;
            *reinterpret_cast<float4*>(&out[4 * (S0 + lane)]) = make_float4(qd1, qd2, qdd1, qdd2);
        }
    }
}

extern "C" void kernel_launch(void* const* d_in, const int* in_sizes, int n_in,
                              void* d_out, int out_size, void* d_ws, size_t ws_size,
                              hipStream_t stream) {
    const float* X  = (const float*)d_in[0];
    const float* W1 = (const float*)d_in[1];
    const float* b1 = (const float*)d_in[2];
    const float* W2 = (const float*)d_in[3];
    const float* b2 = (const float*)d_in[4];
    const float* W3 = (const float*)d_in[5];
    // d_in[6] = b3: constant offset on V, vanishes in all gradients
    float* out = (float*)d_out;
    bf16* ws = (bf16*)d_ws; // 64KB frag images (ws_size assumed >= 65536)
    int B = in_sizes[0] / 4;
    int tiles = (B + 15) >> 4;
    int nchunk = (tiles + GRIDB * NW - 1) / (GRIDB * NW);   // == 1 for B=131072
    prep_kernel<<<16, 256, 0, stream>>>(W2, ws);
    lnn_kernel<<<GRIDB, TPB, 0, stream>>>(X, W1, b1, b2, W3, ws, out, B, nchunk);
}

// Round 19
// 86.315 us; speedup vs baseline: 1.6975x; 1.6975x over previous
//
#include <hip/hip_runtime.h>
#include <math.h>

#define HID 128
#define TPB 512   // 8 waves; 2 blocks/CU (79.5KB LDS x2), 4 waves/SIMD
#define NW  8
#define GRIDB 512 // 2 blocks/CU; 4096 waves x 16 samples x 2 chunks = 131072 = B

typedef __bf16 bf16;
typedef bf16 bf16x8 __attribute__((ext_vector_type(8)));
typedef bf16 bf16x4 __attribute__((ext_vector_type(4)));
typedef float floatx4 __attribute__((ext_vector_type(4)));

__device__ __forceinline__ floatx4 tanh4(floatx4 z) {
    floatx4 t = z * 2.885390081777927f;
    floatx4 e = { __builtin_amdgcn_exp2f(t[0]), __builtin_amdgcn_exp2f(t[1]),
                  __builtin_amdgcn_exp2f(t[2]), __builtin_amdgcn_exp2f(t[3]) };
    e = e + 1.0f;
    floatx4 r = { __builtin_amdgcn_rcpf(e[0]), __builtin_amdgcn_rcpf(e[1]),
                  __builtin_amdgcn_rcpf(e[2]), __builtin_amdgcn_rcpf(e[3]) };
    return 1.0f - 2.0f * r;
}

// FINAL PRODUCTION frame (r16, best measured: bench 87.4us). Session ledger:
//  - allocator pins 64 arch-VGPRs for this kernel regardless of launch_bounds
//    (r2/r7/r10/r12: live>~64 => 200MB scratch spill at 3.5TB/s).
//  - r17: moving weight A-lines LDS->global (for 32 waves/CU) re-spilled via
//    EXTENDED LIVE RANGES of long-latency loads (FETCH 79MB/WRITE 158MB).
//    At a pinned budget, MFMA operands must come from LDS (short, cheap
//    re-issue) not global. Occupancy lever closed.
//  - skew NULL-to-NEGATIVE even spill-free at (512,2) (r15: 91.5 vs 87.8);
//    dual-tile weight-sharing neutral (r9); barrier removal marginal (r6);
//    r13 ablation: cost distributed across phases, no dominant pipe
//    (VALU 50%, Mfma 17%); setprio neutral-to-positive, kept (r16).
//
// Structure: wave-autonomous, 16 samples/wave/chunk, 2 chunks, no in-loop
// barriers. MFMA 16x16x32 layouts:
//   A-frag: lane holds A[m=lane&15][k=(lane>>4)*8+idx]
//   B-frag: lane holds B[k=(lane>>4)*8+idx][n=lane&15]
//   C/D:    lane/reg holds D[row=(lane>>4)*4+reg][col=lane&15]
// Sample ALWAYS = lane&15. P1 makes H1^T B-frags directly in regs (breg).
// GEMM1t: Z2^T = W2^T @ H1^T (A=sW2A lines, B=breg)
// GEMM2t: S^T  = W2 @ G2^T   (A=sW2R lines, B=gB via line transform)
// GEMM3t: dV^T = W1 @ G1^T   (A=sW1A lines, B=(1-breg^2)*transform(S))
// C->B transform (HW-verified r7-r16): line L, b: elem = lrow*32 + blk*8 +
// 4(lq&1)+r, blk=(2b+(lq>>1))^(lrow&3); read b128 at lrow*32+(lq^(lrow&3))*8.
// DS in-order per wave => write->read needs no barrier.

__global__ __launch_bounds__(TPB, 4)
void lnn_kernel(const float* __restrict__ X,
                const float* __restrict__ W1,
                const float* __restrict__ b1,
                const float* __restrict__ b2,
                const float* __restrict__ W3,
                const float* __restrict__ W2,
                float* __restrict__ out,
                int B, int nchunk)
{
    __shared__ __align__(16) bf16 sW2A[16384]; // 32KB W2^T A-frags
    __shared__ __align__(16) bf16 sW2R[16384]; // 32KB W2 row A-frags
    __shared__ __align__(16) bf16 sXf[NW][512]; // 8KB per-wave line buffers
    __shared__ __align__(16) bf16 sW1A[4][512]; // 4KB W1 A-frag lines
    __shared__ __align__(16) float sW1r[4][HID];
    __shared__ __align__(16) float sB1[HID], sB2[HID], sW3[HID];

    const int tid  = threadIdx.x;
    const int w    = tid >> 6;
    const int lane = tid & 63;
    const int lrow = lane & 15;
    const int lq   = lane >> 4;
    const int swz  = lrow & 3;

    { int r = tid >> 7, j = tid & (HID - 1); sW1r[r][j] = W1[r * HID + j]; }
    if (tid < HID) sB1[tid] = b1[tid];
    else if (tid < 2 * HID) sB2[tid - HID] = b2[tid - HID];
    else if (tid < 3 * HID) sW3[tid - 2 * HID] = W3[tid - 2 * HID];

    #pragma unroll
    for (int tt = 0; tt < 4; ++tt) {
        int e = tid + tt * TPB;
        int t = e >> 6, l = e & 63;
        int a = t >> 2, bidx = t & 3;
        int lr = l & 15, q = l >> 4;
        bf16x8 f;
        #pragma unroll
        for (int idx = 0; idx < 8; ++idx)
            f[idx] = (bf16)W2[(32*bidx + 8*q + idx) * HID + 16*a + lr];
        *reinterpret_cast<bf16x8*>(&sW2A[e * 8]) = f;
        const float4* rp = reinterpret_cast<const float4*>(&W2[(16*a + lr) * HID + 32*bidx + 8*q]);
        float4 r0 = rp[0], r1 = rp[1];
        bf16x8 g;
        g[0]=(bf16)r0.x; g[1]=(bf16)r0.y; g[2]=(bf16)r0.z; g[3]=(bf16)r0.w;
        g[4]=(bf16)r1.x; g[5]=(bf16)r1.y; g[6]=(bf16)r1.z; g[7]=(bf16)r1.w;
        *reinterpret_cast<bf16x8*>(&sW2R[e * 8]) = g;
    }
    if (tid < 256) {
        int m = tid >> 6, l = tid & 63;
        int lr = l & 15, q = l >> 4;
        bf16x8 f = {};
        if (lr < 4) {
            #pragma unroll
            for (int idx = 0; idx < 8; ++idx)
                f[idx] = (bf16)W1[lr * HID + 32*m + 8*q + idx];
        }
        *reinterpret_cast<bf16x8*>(&sW1A[m][l * 8]) = f;
    }
    __syncthreads(); // only barrier

    bf16* const lb = &sXf[w][0];
    const int tileStride = GRIDB * NW;
    const int t0 = (int)blockIdx.x * NW + w;
    const floatx4 fz = floatx4{0.f,0.f,0.f,0.f};

    #pragma unroll 1
    for (int c = 0; c < nchunk; ++c) {
        const int tile = t0 + c * tileStride;
        if (tile * 16 >= B) break;
        const int S0 = tile * 16;

        int gc = S0 + lrow; gc = gc < B ? gc : (B - 1);
        float4 xc = reinterpret_cast<const float4*>(X)[gc];
        float s1c, c1c, s2c, c2c;
        __sincosf(xc.x, &s1c, &c1c);
        __sincosf(xc.y, &s2c, &c2c);

        // ---- P1: feat -> H1^T B-frags in regs ----
        bf16x8 bregc[4];
        #pragma unroll
        for (int kt = 0; kt < 4; ++kt) {
            int jb = 32 * kt + 8 * lq;
            floatx4 w0a = *reinterpret_cast<const floatx4*>(&sW1r[0][jb]);
            floatx4 w0b = *reinterpret_cast<const floatx4*>(&sW1r[0][jb+4]);
            floatx4 w1a = *reinterpret_cast<const floatx4*>(&sW1r[1][jb]);
            floatx4 w1b = *reinterpret_cast<const floatx4*>(&sW1r[1][jb+4]);
            floatx4 w2a = *reinterpret_cast<const floatx4*>(&sW1r[2][jb]);
            floatx4 w2b = *reinterpret_cast<const floatx4*>(&sW1r[2][jb+4]);
            floatx4 w3a = *reinterpret_cast<const floatx4*>(&sW1r[3][jb]);
            floatx4 w3b = *reinterpret_cast<const floatx4*>(&sW1r[3][jb+4]);
            floatx4 bba = *reinterpret_cast<const floatx4*>(&sB1[jb]);
            floatx4 bbb = *reinterpret_cast<const floatx4*>(&sB1[jb+4]);
            floatx4 za = bba + s1c*w0a + c1c*w1a + s2c*w2a + c2c*w3a;
            floatx4 zb = bbb + s1c*w0b + c1c*w1b + s2c*w2b + c2c*w3b;
            floatx4 ha = tanh4(za), hb = tanh4(zb);
            bf16x8 hf;
            hf[0]=(bf16)ha[0]; hf[1]=(bf16)ha[1]; hf[2]=(bf16)ha[2]; hf[3]=(bf16)ha[3];
            hf[4]=(bf16)hb[0]; hf[5]=(bf16)hb[1]; hf[6]=(bf16)hb[2]; hf[7]=(bf16)hb[3];
            bregc[kt] = hf;
        }

        // ---- GEMM1 + P3 writes + gB reads (line-by-line, rolling acc) ----
        bf16x8 gB[4];
        #pragma unroll
        for (int L = 0; L < 4; ++L) {
            #pragma unroll
            for (int b = 0; b < 2; ++b) {
                int jt = 2*L + b;
                __builtin_amdgcn_s_setprio(1);
                floatx4 acc = __builtin_amdgcn_mfma_f32_16x16x32_bf16(
                    *reinterpret_cast<const bf16x8*>(&sW2A[((jt*4 + 0)*64 + lane)*8]),
                    bregc[0], fz, 0,0,0);
                #pragma unroll
                for (int kt = 1; kt < 4; ++kt)
                    acc = __builtin_amdgcn_mfma_f32_16x16x32_bf16(
                        *reinterpret_cast<const bf16x8*>(&sW2A[((jt*4 + kt)*64 + lane)*8]),
                        bregc[kt], acc, 0,0,0);
                __builtin_amdgcn_s_setprio(0);
                int jb = 16*jt + 4*lq;
                floatx4 b2v = *reinterpret_cast<const floatx4*>(&sB2[jb]);
                floatx4 w3v = *reinterpret_cast<const floatx4*>(&sW3[jb]);
                floatx4 h = tanh4(acc + b2v);
                floatx4 gv = (1.0f - h*h) * w3v;
                bf16x4 g;
                g[0]=(bf16)gv[0]; g[1]=(bf16)gv[1]; g[2]=(bf16)gv[2]; g[3]=(bf16)gv[3];
                int blk = (2*b + (lq>>1)) ^ swz;
                *reinterpret_cast<bf16x4*>(&lb[lrow*32 + blk*8 + 4*(lq&1)]) = g;
            }
            gB[L] = *reinterpret_cast<const bf16x8*>(&lb[lrow*32 + (lq ^ swz)*8]);
        }

        // ---- GEMM2 + P5 writes + GEMM3 (line-by-line, rolling acc) ----
        floatx4 dv = fz;
        #pragma unroll
        for (int L = 0; L < 4; ++L) {
            #pragma unroll
            for (int b = 0; b < 2; ++b) {
                int it = 2*L + b;
                __builtin_amdgcn_s_setprio(1);
                floatx4 acc2 = __builtin_amdgcn_mfma_f32_16x16x32_bf16(
                    *reinterpret_cast<const bf16x8*>(&sW2R[((it*4 + 0)*64 + lane)*8]),
                    gB[0], fz, 0,0,0);
                #pragma unroll
                for (int jt2 = 1; jt2 < 4; ++jt2)
                    acc2 = __builtin_amdgcn_mfma_f32_16x16x32_bf16(
                        *reinterpret_cast<const bf16x8*>(&sW2R[((it*4 + jt2)*64 + lane)*8]),
                        gB[jt2], acc2, 0,0,0);
                __builtin_amdgcn_s_setprio(0);
                bf16x4 g;
                g[0]=(bf16)acc2[0]; g[1]=(bf16)acc2[1];
                g[2]=(bf16)acc2[2]; g[3]=(bf16)acc2[3];
                int blk = (2*b + (lq>>1)) ^ swz;
                *reinterpret_cast<bf16x4*>(&lb[lrow*32 + blk*8 + 4*(lq&1)]) = g;
            }
            bf16x8 sv = *reinterpret_cast<const bf16x8*>(&lb[lrow*32 + (lq ^ swz)*8]);
            bf16x8 A3 = *reinterpret_cast<const bf16x8*>(&sW1A[L][lane*8]);
            bf16x8 g1;
            #pragma unroll
            for (int idx = 0; idx < 8; ++idx) {
                float h = (float)bregc[L][idx];
                float s = (float)sv[idx];
                g1[idx] = (bf16)(s - s*h*h);
            }
            __builtin_amdgcn_s_setprio(1);
            dv = __builtin_amdgcn_mfma_f32_16x16x32_bf16(A3, g1, dv, 0,0,0);
            __builtin_amdgcn_s_setprio(0);
        }

        // ---- Epilogue: lanes 0..15 hold dv rows 0..3 for sample lrow ----
        if (lane < 16 && S0 + lane < B) {
            float dV0 = dv[0], dV1 = dv[1], dV2 = dv[2], dV3 = dv[3];
            float cosD = c1c * c2c + s1c * s2c;
            float sinD = s1c * c2c - c1c * s2c;
            float dVt1 = dV0 * c1c - dV1 * s1c;   // dV/dt1
            float dVt2 = dV2 * c2c - dV3 * s2c;   // dV/dt2
            float qd1 = xc.z, qd2 = xc.w;
            float sT = qd1 * qd2 * sinD;          // dT/dt1 = -sT, dT/dt2 = +sT
            float cw = sinD * (qd2 - qd1);
            float rhs1 = (-sT - dVt1) - qd2 * cw;
            float rhs2 = ( sT - dVt2) - qd1 * cw;
            float det = 2.0f - cosD * cosD;       // det(M) in [1,2]
            float inv = __builtin_amdgcn_rcpf(det);
            float qdd1 = (rhs1 - cosD * rhs2) * inv;
            float qdd2 = (2.0f * rhs2 - cosD * rhs1) * inv;
            *reinterpret_cast<float4*>(&out[4 * (S0 + lane)]) = make_float4(qd1, qd2, qdd1, qdd2);
        }
    }
}

extern "C" void kernel_launch(void* const* d_in, const int* in_sizes, int n_in,
                              void* d_out, int out_size, void* d_ws, size_t ws_size,
                              hipStream_t stream) {
    const float* X  = (const float*)d_in[0];
    const float* W1 = (const float*)d_in[1];
    const float* b1 = (const float*)d_in[2];
    const float* W2 = (const float*)d_in[3];
    const float* b2 = (const float*)d_in[4];
    const float* W3 = (const float*)d_in[5];
    // d_in[6] = b3: constant offset on V, vanishes in all gradients
    float* out = (float*)d_out;
    int B = in_sizes[0] / 4;
    int tiles = (B + 15) >> 4;
    int nchunk = (tiles + GRIDB * NW - 1) / (GRIDB * NW);   // == 2 for B=131072
    lnn_kernel<<<GRIDB, TPB, 0, stream>>>(X, W1, b1, b2, W3, W2, out, B, nchunk);
}